// Round 15
// baseline (207.182 us; speedup 1.0000x reference)
//
#include <hip/hip_runtime.h>

#define NSTEPS 64

typedef __attribute__((ext_vector_type(16))) float float16_;   // 32x32 MFMA C/D
typedef __attribute__((ext_vector_type(2)))  __fp16 half2_;    // packed f16
typedef __attribute__((ext_vector_type(8)))  __fp16 half8_;    // f16 MFMA A/B operand

__device__ __forceinline__ half2_ relu_pk_f16(float a, float b) {
    half2_ h = __builtin_amdgcn_cvt_pkrtz(a, b);               // v_cvt_pkrtz_f16_f32
    return __builtin_elementwise_max(h, (half2_)(__fp16)0);    // v_pk_max_f16
}

// R28 (resubmitted — R14 was an infra failure, kernel never measured):
// z-space schedule ported to the 32x32 shape.
// Evidence: R6 (32-shape) VALU-busy 90us < R13 (16-shape z-space) 108us
// despite fewer modeled instr at 16-shape => ~half of VALU time is operand
// marshaling scaling with FRAGMENT COUNT; 32-shape halves fragments/sample.
// R13's z-space cut MFMA-busy 74.5->62us. This round combines both.
//
// 32x32x16 layout (HW-verified R1-R6):
//   A[m][k]: m=lane&31, k=(lane>>5)*8+j ; B same ; C/D[r][c]: c=lane&31,
//   r=(reg&3)+8*(reg>>2)+4*(lane>>5).
// Pack path (validated R6): lo.h2[pp]=pk(D[2pp],D[2pp+1]) -> slots 8h+j;
//   hi.h2[pp]=pk(D[8+2pp],..) -> slots 16+8h+j. Slot k holds unit
//   nu(k) = 16*(k>>4) + 4*((k>>3)&1) + (k&3) + 8*((k&7)>>2).
// Self-consistency (new derivation): nu(kappa(r)) == r, so positions carry
// IDENTITY unit order; all A-operands are nu-indexed on k, identity on m.
// z-space algebra (validated R9-R13): zb=y*W1+b1 state in D-layout;
//   M=W3*W1; cH=dt2*(b3*W1); st1/2: C=zb+cH, M(dt2); st3: C=zb+2cH,
//   feed 2*Q into M(dt2); zb'=Mz(dt6)*S + (zb+2cH); S=Q0+2Q1+2Q2+Q3;
//   y_T = y0 + dt6*(SSUM*W3) + T*dt*b3 at the 8 sampled steps only.
// 16 MFMAs/step; L3 sampled-only. Mf dropped (Qd=2Q) for register margin.
// (256,3) cap 170 vs ~165 demand; spill tripwire = WRITE_SIZE.
__global__ __launch_bounds__(256, 3)
void ode_rk4_mfma(const float* __restrict__ x,
                  const float* __restrict__ samples,
                  const float* __restrict__ w1, const float* __restrict__ b1,
                  const float* __restrict__ w2, const float* __restrict__ b2,
                  const float* __restrict__ w3, const float* __restrict__ b3,
                  const float* __restrict__ w_out, const float* __restrict__ b_out,
                  float* __restrict__ out, int B)
{
    const int lane  = threadIdx.x & 63;
    const int w     = threadIdx.x >> 6;
    const int col32 = lane & 31;              // this lane's sample (mod 32)
    const int half  = lane >> 5;              // 0..1

    const int row = (blockIdx.x * 4 + w) * 32 + col32;

    // slot k -> unit
    auto nu = [](int k) -> int {
        return 16 * (k >> 4) + 4 * ((k >> 3) & 1) + (k & 3) + 8 * (((k & 7)) >> 2);
    };
    // D-position from reg t and half h
    auto rpos = [&](int t) -> int { return (t & 3) + 8 * (t >> 2) + 4 * half; };

    // ---- scalars ----
    const float maxT = samples[7];
    const float dt   = maxT / 64.0f;
    const float dt2  = 0.5f * dt;
    const float dt6  = dt / 6.0f;

    union F { half2_ h2[4]; half8_ h8; };

    // ---- persistent MFMA operands ----
    // M = W3*W1; Mh (dt2-scaled) and Mz (dt6) as two K-half frags each.
    // A[m][k-slot] = ci * M[nu(k)][m].
    F Mh1, Mh2, Mz1, Mz2;
#pragma unroll
    for (int pp = 0; pp < 4; ++pp) {
        int j0 = 2 * pp;
        int iA = nu(8 * half + j0),      iB = nu(8 * half + j0 + 1);
        int iC = nu(16 + 8 * half + j0), iD = nu(16 + 8 * half + j0 + 1);
        float mA = w3[iA * 3 + 0] * w1[0 * 32 + col32] + w3[iA * 3 + 1] * w1[1 * 32 + col32] + w3[iA * 3 + 2] * w1[2 * 32 + col32];
        float mB = w3[iB * 3 + 0] * w1[0 * 32 + col32] + w3[iB * 3 + 1] * w1[1 * 32 + col32] + w3[iB * 3 + 2] * w1[2 * 32 + col32];
        float mC = w3[iC * 3 + 0] * w1[0 * 32 + col32] + w3[iC * 3 + 1] * w1[1 * 32 + col32] + w3[iC * 3 + 2] * w1[2 * 32 + col32];
        float mD = w3[iD * 3 + 0] * w1[0 * 32 + col32] + w3[iD * 3 + 1] * w1[1 * 32 + col32] + w3[iD * 3 + 2] * w1[2 * 32 + col32];
        Mh1.h2[pp] = (half2_){(__fp16)(dt2 * mA), (__fp16)(dt2 * mB)};
        Mh2.h2[pp] = (half2_){(__fp16)(dt2 * mC), (__fp16)(dt2 * mD)};
        Mz1.h2[pp] = (half2_){(__fp16)(dt6 * mA), (__fp16)(dt6 * mB)};
        Mz2.h2[pp] = (half2_){(__fp16)(dt6 * mC), (__fp16)(dt6 * mD)};
    }

    // Layer2: A2[m][k-slot] = w2[nu(k)*32 + m]; two K-half frags.
    F W2T1, W2T2;
#pragma unroll
    for (int pp = 0; pp < 4; ++pp) {
        int j0 = 2 * pp;
        int iA = nu(8 * half + j0),      iB = nu(8 * half + j0 + 1);
        int iC = nu(16 + 8 * half + j0), iD = nu(16 + 8 * half + j0 + 1);
        W2T1.h2[pp] = (half2_){(__fp16)w2[iA * 32 + col32], (__fp16)w2[iB * 32 + col32]};
        W2T2.h2[pp] = (half2_){(__fp16)w2[iC * 32 + col32], (__fp16)w2[iD * 32 + col32]};
    }
    // layer2 bias C-frag (identity position order)
    float16_ Cb;
#pragma unroll
    for (int r = 0; r < 16; ++r)
        Cb[r] = b2[rpos(r)];

    // Layer3 A-frags with row duplication: rows m<8 with (m&3)<3 carry
    // w3 column (m&3) -> D3 regs 0..2 hold k_d in BOTH halves.
    F A31, A32;
    {
        const int  d    = col32 & 3;
        const bool live = (col32 < 8) && (d < 3);
#pragma unroll
        for (int pp = 0; pp < 4; ++pp) {
            int j0 = 2 * pp;
            int iA = nu(8 * half + j0),      iB = nu(8 * half + j0 + 1);
            int iC = nu(16 + 8 * half + j0), iD = nu(16 + 8 * half + j0 + 1);
            A31.h2[pp] = live ? (half2_){(__fp16)w3[iA * 3 + d], (__fp16)w3[iB * 3 + d]} : (half2_)(__fp16)0.0f;
            A32.h2[pp] = live ? (half2_){(__fp16)w3[iC * 3 + d], (__fp16)w3[iD * 3 + d]} : (half2_)(__fp16)0.0f;
        }
    }

    // cH = dt2*(b3*W1) in D-layout (identity order)
    float16_ cH;
#pragma unroll
    for (int r = 0; r < 16; ++r) {
        int u = rpos(r);
        cH[r] = dt2 * (b3[0] * w1[0 * 32 + u] + b3[1] * w1[1 * 32 + u] + b3[2] * w1[2 * 32 + u]);
    }

    int sidx[8];
    unsigned long long smask = 0ull;
#pragma unroll
    for (int j = 0; j < 8; ++j) {
        int id = (int)rintf(samples[j] / dt) - 1;   // jnp.round = RNE
        id = id < 0 ? 0 : (id > NSTEPS - 1 ? NSTEPS - 1 : id);
        id = __builtin_amdgcn_readfirstlane(id);    // wave-uniform -> SGPR
        sidx[j] = id;
        smask |= 1ull << id;
    }
    const float wo0 = w_out[0], wo1 = w_out[1], wo2 = w_out[2];
    const float bo  = b_out[0];
    const float db0 = dt * b3[0], db1 = dt * b3[1], db2 = dt * b3[2];

    const float y00 = x[(size_t)row * 3 + 0];
    const float y01 = x[(size_t)row * 3 + 1];
    const float y02 = x[(size_t)row * 3 + 2];

    // ---- prologue: zb = y*W1 + b1 in D-layout (identity m, one MFMA) ----
    float16_ zb;
    {
        F A1y;
        if (half == 0) {
            A1y.h2[0] = (half2_){(__fp16)w1[0 * 32 + col32], (__fp16)w1[1 * 32 + col32]};
            A1y.h2[1] = (half2_){(__fp16)w1[2 * 32 + col32], (__fp16)b1[col32]};
            A1y.h2[2] = (half2_)(__fp16)0.0f;
            A1y.h2[3] = (half2_)(__fp16)0.0f;
        } else {
#pragma unroll
            for (int pp = 0; pp < 4; ++pp) A1y.h2[pp] = (half2_)(__fp16)0.0f;
        }
        float16_ Zc;
#pragma unroll
        for (int r = 0; r < 16; ++r) Zc[r] = 0.0f;
        half2_ a = __builtin_amdgcn_cvt_pkrtz(y00, y01);
        half2_ b = __builtin_amdgcn_cvt_pkrtz(y02, 1.0f);
        F By;
        By.h2[0] = a; By.h2[1] = b; By.h2[2] = a; By.h2[3] = b;
        zb = __builtin_amdgcn_mfma_f32_32x32x16_f16(A1y.h8, By.h8, Zc, 0, 0, 0);
    }

    const half2_ two = (half2_)(__fp16)2.0f;
    F SSl, SSh;   // SSUM, packed f16 (lo/hi K-half frags)
#pragma unroll
    for (int pp = 0; pp < 4; ++pp) { SSl.h2[pp] = (half2_)(__fp16)0.0f; SSh.h2[pp] = (half2_)(__fp16)0.0f; }

#pragma unroll 1
    for (int s = 0; s < NSTEPS; ++s) {
        F Pl, Ph, Ql, Qh, Sl, Sh;

        // ---- st0: P directly from zb (D regs -> lo/hi frags, R6 pack) ----
#pragma unroll
        for (int pp = 0; pp < 4; ++pp) {
            Pl.h2[pp] = relu_pk_f16(zb[2 * pp],     zb[2 * pp + 1]);
            Ph.h2[pp] = relu_pk_f16(zb[8 + 2 * pp], zb[8 + 2 * pp + 1]);
        }
        float16_ D2 = __builtin_amdgcn_mfma_f32_32x32x16_f16(W2T2.h8, Ph.h8,
                      __builtin_amdgcn_mfma_f32_32x32x16_f16(W2T1.h8, Pl.h8, Cb, 0, 0, 0), 0, 0, 0);
#pragma unroll
        for (int pp = 0; pp < 4; ++pp) {
            Sl.h2[pp] = relu_pk_f16(D2[2 * pp],     D2[2 * pp + 1]);   // Q0 -> S (ca=1)
            Sh.h2[pp] = relu_pk_f16(D2[8 + 2 * pp], D2[8 + 2 * pp + 1]);
        }

        float16_ zh = zb + cH;                 // C for st1/st2

        // ---- st1 (B = S == Q0; ca=2) ----
        {
            float16_ G = __builtin_amdgcn_mfma_f32_32x32x16_f16(Mh2.h8, Sh.h8,
                         __builtin_amdgcn_mfma_f32_32x32x16_f16(Mh1.h8, Sl.h8, zh, 0, 0, 0), 0, 0, 0);
#pragma unroll
            for (int pp = 0; pp < 4; ++pp) {
                Pl.h2[pp] = relu_pk_f16(G[2 * pp],     G[2 * pp + 1]);
                Ph.h2[pp] = relu_pk_f16(G[8 + 2 * pp], G[8 + 2 * pp + 1]);
            }
            float16_ E = __builtin_amdgcn_mfma_f32_32x32x16_f16(W2T2.h8, Ph.h8,
                         __builtin_amdgcn_mfma_f32_32x32x16_f16(W2T1.h8, Pl.h8, Cb, 0, 0, 0), 0, 0, 0);
#pragma unroll
            for (int pp = 0; pp < 4; ++pp) {
                Ql.h2[pp] = relu_pk_f16(E[2 * pp],     E[2 * pp + 1]);
                Qh.h2[pp] = relu_pk_f16(E[8 + 2 * pp], E[8 + 2 * pp + 1]);
                Sl.h2[pp] += two * Ql.h2[pp];
                Sh.h2[pp] += two * Qh.h2[pp];
            }
        }

        // ---- st2 (B = Q1; ca=2) ----
        {
            float16_ G = __builtin_amdgcn_mfma_f32_32x32x16_f16(Mh2.h8, Qh.h8,
                         __builtin_amdgcn_mfma_f32_32x32x16_f16(Mh1.h8, Ql.h8, zh, 0, 0, 0), 0, 0, 0);
#pragma unroll
            for (int pp = 0; pp < 4; ++pp) {
                Pl.h2[pp] = relu_pk_f16(G[2 * pp],     G[2 * pp + 1]);
                Ph.h2[pp] = relu_pk_f16(G[8 + 2 * pp], G[8 + 2 * pp + 1]);
            }
            float16_ E = __builtin_amdgcn_mfma_f32_32x32x16_f16(W2T2.h8, Ph.h8,
                         __builtin_amdgcn_mfma_f32_32x32x16_f16(W2T1.h8, Pl.h8, Cb, 0, 0, 0), 0, 0, 0);
#pragma unroll
            for (int pp = 0; pp < 4; ++pp) {
                Ql.h2[pp] = relu_pk_f16(E[2 * pp],     E[2 * pp + 1]);
                Qh.h2[pp] = relu_pk_f16(E[8 + 2 * pp], E[8 + 2 * pp + 1]);
                Sl.h2[pp] += two * Ql.h2[pp];
                Sh.h2[pp] += two * Qh.h2[pp];
            }
        }

        // ---- st3 (ca=1): C = zb+2cH; feed 2*Q into dt2-scaled M ----
        zh = zh + cH;                          // zh = zb + 2*cH
        {
            F Qdl, Qdh;
#pragma unroll
            for (int pp = 0; pp < 4; ++pp) {
                Qdl.h2[pp] = Ql.h2[pp] + Ql.h2[pp];   // exact x2
                Qdh.h2[pp] = Qh.h2[pp] + Qh.h2[pp];
            }
            float16_ G = __builtin_amdgcn_mfma_f32_32x32x16_f16(Mh2.h8, Qdh.h8,
                         __builtin_amdgcn_mfma_f32_32x32x16_f16(Mh1.h8, Qdl.h8, zh, 0, 0, 0), 0, 0, 0);
#pragma unroll
            for (int pp = 0; pp < 4; ++pp) {
                Pl.h2[pp] = relu_pk_f16(G[2 * pp],     G[2 * pp + 1]);
                Ph.h2[pp] = relu_pk_f16(G[8 + 2 * pp], G[8 + 2 * pp + 1]);
            }
            float16_ E = __builtin_amdgcn_mfma_f32_32x32x16_f16(W2T2.h8, Ph.h8,
                         __builtin_amdgcn_mfma_f32_32x32x16_f16(W2T1.h8, Pl.h8, Cb, 0, 0, 0), 0, 0, 0);
#pragma unroll
            for (int pp = 0; pp < 4; ++pp) {
                Ql.h2[pp] = relu_pk_f16(E[2 * pp],     E[2 * pp + 1]);
                Qh.h2[pp] = relu_pk_f16(E[8 + 2 * pp], E[8 + 2 * pp + 1]);
                Sl.h2[pp] += Ql.h2[pp];                // ca=1
                Sh.h2[pp] += Qh.h2[pp];
            }
        }

        // ---- SSUM accumulate + z-update (C-operand = zh = zb+2cH) ----
#pragma unroll
        for (int pp = 0; pp < 4; ++pp) { SSl.h2[pp] += Sl.h2[pp]; SSh.h2[pp] += Sh.h2[pp]; }
        zb = __builtin_amdgcn_mfma_f32_32x32x16_f16(Mz2.h8, Sh.h8,
             __builtin_amdgcn_mfma_f32_32x32x16_f16(Mz1.h8, Sl.h8, zh, 0, 0, 0), 0, 0, 0);

        // ---- sampled steps only: reconstruct y and store ----
        if ((smask >> s) & 1ull) {
            float16_ Zc;
#pragma unroll
            for (int r = 0; r < 16; ++r) Zc[r] = 0.0f;
            float16_ D3 = __builtin_amdgcn_mfma_f32_32x32x16_f16(A32.h8, SSh.h8,
                          __builtin_amdgcn_mfma_f32_32x32x16_f16(A31.h8, SSl.h8, Zc, 0, 0, 0), 0, 0, 0);
            float T = (float)(s + 1);
            float o0 = fmaf(dt6, D3[0], fmaf(T, db0, y00));
            float o1 = fmaf(dt6, D3[1], fmaf(T, db1, y01));
            float o2 = fmaf(dt6, D3[2], fmaf(T, db2, y02));
            if (half == 0) {
#pragma unroll
                for (int j = 0; j < 8; ++j) {
                    if (sidx[j] == s) {
                        out[(size_t)j * B + row] = fmaf(o2, wo2, fmaf(o1, wo1, fmaf(o0, wo0, bo)));
                    }
                }
            }
        }
    }
}

extern "C" void kernel_launch(void* const* d_in, const int* in_sizes, int n_in,
                              void* d_out, int out_size, void* d_ws, size_t ws_size,
                              hipStream_t stream) {
    const float* x       = (const float*)d_in[0];
    const float* samples = (const float*)d_in[1];
    const float* w1      = (const float*)d_in[2];
    const float* b1      = (const float*)d_in[3];
    const float* w2      = (const float*)d_in[4];
    const float* b2      = (const float*)d_in[5];
    const float* w3      = (const float*)d_in[6];
    const float* b3      = (const float*)d_in[7];
    const float* w_out   = (const float*)d_in[8];
    const float* b_out   = (const float*)d_in[9];
    float* out = (float*)d_out;

    const int B = in_sizes[0] / 3;           // 131072
    const int rowsPerBlock = 128;            // 4 waves x 32 samples
    const int grid = (B + rowsPerBlock - 1) / rowsPerBlock;   // 1024
    ode_rk4_mfma<<<grid, 256, 0, stream>>>(
        x, samples, w1, b1, w2, b2, w3, b3, w_out, b_out, out, B);
}